// Round 1
// baseline (347.990 us; speedup 1.0000x reference)
//
#include <hip/hip_runtime.h>

#define HIDDEN 2048
#define NHEADS 32
#define NKV    8
#define HDIM   64
#define BATCH  2
#define SEQ    2048
#define MROWS  (BATCH*SEQ)          // 4096
#define NQKV   3072                 // 2048 Q + 512 K + 512 V

// scale 1/sqrt(64) * log2(e): folded into Wq/bq so softmax uses native exp2
#define SCALEQ 0.18033688011112042f

typedef _Float16 half8_t __attribute__((ext_vector_type(8)));
typedef _Float16 half4_t __attribute__((ext_vector_type(4)));
typedef __fp16   fp16x2_t __attribute__((ext_vector_type(2)));
typedef float    f32x4_t __attribute__((ext_vector_type(4)));

#define AS1 __attribute__((address_space(1)))
#define AS3 __attribute__((address_space(3)))

__device__ __forceinline__ void async_copy16(void* lds, const void* g) {
    // LDS dest = wave-uniform base + lane*16 (m104/m108)
    __builtin_amdgcn_global_load_lds((AS1 void*)g, (AS3 void*)lds, 16, 0, 0);
}

#define PRIO1 __builtin_amdgcn_s_setprio(1)
#define PRIO0 __builtin_amdgcn_s_setprio(0)
#define BAR   __builtin_amdgcn_s_barrier()

// ---------------------------------------------------------------------------
// 256x256 8-phase NT GEMM (T2+T3+T4+T5 stack, per the m201 template spec).
//   8 waves (512 thr), wave (wr,wc)=(w>>2, w&3) owns a 128x64 output tile.
//   BK=64 K-tiles; LDS 2dbuf x (A 256x64 + B 256x64) fp16 = 128 KiB.
//   Swizzle: logical (row, k-granule g[16B]) stored at granule g ^ (row&7).
//     global_load_lds writes LINEARLY, so the SOURCE address carries the
//     inverse (== same) permutation and the ds_read applies it again
//     (both-sides-or-neither, rule 21). ds_read_b128 of a fragment column
//     then spreads 16 rows across 8 bank-quads -> 2-way (free).
//   Per K-tile phases (quadrants (mh,nh) in order 00,01,11,10):
//     ph1: ds A-mh0(8) + B-all(8) | ph2: ds A-mh1(8) | ph3,ph4: pure MFMA.
//   Staging: 1 half-tile (2 global_load_lds/thread) per phase, issued >=1
//   barrier after the last read of its dest region:
//     buf0 B free after ph1 -> issue ph2(Bh0),ph3(Bh1); A free after ph2
//     -> ph4(Ah0),ph5(Ah1); buf1 B free after ph5 -> ph6,ph7; A free after
//     ph6 -> ph8(Ah0), next-ph1(Ah1).
//   Waits: vmcnt(6) at ph4 (covers through ph1's issue; 3-phase latency
//   cover) and ph8 (covers through ph5); vmcnt(0) only in the last iter.
// ---------------------------------------------------------------------------

#define LDA(dst, bi, mh) do {                                                  \
    _Pragma("unroll") for (int mi = 0; mi < 4; ++mi) {                         \
        dst[mi][0] = *(const half8_t*)(&As[bi][abase + (mh)*4096 + mi*1024 + g0]); \
        dst[mi][1] = *(const half8_t*)(&As[bi][abase + (mh)*4096 + mi*1024 + g1]); \
    } } while (0)

#define LDB(dst, bi) do {                                                      \
    _Pragma("unroll") for (int ni = 0; ni < 4; ++ni) {                         \
        dst[ni][0] = *(const half8_t*)(&Bs[bi][bbase + ni*1024 + g0]);         \
        dst[ni][1] = *(const half8_t*)(&Bs[bi][bbase + ni*1024 + g1]);         \
    } } while (0)

#define MFMA_Q(av, bv, mh, nh) do {                                            \
    _Pragma("unroll") for (int mi = 0; mi < 4; ++mi)                           \
    _Pragma("unroll") for (int ni = 0; ni < 2; ++ni) {                         \
        f32x4_t& cc = acc[(mh)*4 + mi][(nh)*2 + ni];                           \
        cc = __builtin_amdgcn_mfma_f32_16x16x32_f16(av[mi][0], bv[(nh)*2+ni][0], cc, 0, 0, 0); \
        cc = __builtin_amdgcn_mfma_f32_16x16x32_f16(av[mi][1], bv[(nh)*2+ni][1], cc, 0, 0, 0); \
    } } while (0)

// stage one half-tile (128 rows x 64 k) of A or B: 2 x global_load_lds/thread
#define STG_AH(bi, hf, kb) do {                                                \
    async_copy16(&As[bi][(hf)*8192 + ldst],        Ag + (size_t)((hf)*128)      * K + (kb)); \
    async_copy16(&As[bi][(hf)*8192 + 4096 + ldst], Ag + (size_t)((hf)*128 + 64) * K + (kb)); \
  } while (0)
#define STG_BH(bi, hf, kb) do {                                                \
    async_copy16(&Bs[bi][(hf)*8192 + ldst],        Bg + (size_t)((hf)*128)      * K + (kb)); \
    async_copy16(&Bs[bi][(hf)*8192 + 4096 + ldst], Bg + (size_t)((hf)*128 + 64) * K + (kb)); \
  } while (0)

template <typename OutT, bool QKV>
__global__ __launch_bounds__(512, 2) void gemm256(
    const _Float16* __restrict__ A, const _Float16* __restrict__ Bm,
    const float* __restrict__ bias, OutT* __restrict__ C,
    _Float16* __restrict__ kfb, _Float16* __restrict__ vfb,
    int K, int ldc) {
    __shared__ _Float16 As[2][16384];   // [buf][half*8192 + row*64 + swz-granule]
    __shared__ _Float16 Bs[2][16384];

    const int tid  = threadIdx.x;
    const int wave = tid >> 6;
    const int lane = tid & 63;
    const int quad = lane >> 4;
    const int l16  = lane & 15;
    const int wr   = wave >> 2;          // 0..1 : wave row (128 rows)
    const int wc   = wave & 3;           // 0..3 : wave col (64 cols)

    // bijective XCD swizzle (nwg % 8 == 0 at both call sites)
    const int nwg = (int)(gridDim.x * gridDim.y);
    const int lin = (int)(blockIdx.y * gridDim.x + blockIdx.x);
    const int q8  = nwg >> 3;
    const int idx = (lin & 7) * q8 + (lin >> 3);
    const int tx  = idx % (int)gridDim.x;
    const int ty  = idx / (int)gridDim.x;
    const int m0  = ty * 256;
    const int n0  = tx * 256;

    // staging source: thread t covers (row = t>>3, granule = t&7) of each
    // 64-row issue; source granule pre-swizzled by row&7 (= (t>>3)&7).
    const int srow = tid >> 3;                       // 0..63
    const int sg   = ((tid & 7) ^ (srow & 7)) << 3;  // halves
    const _Float16* Ag = A  + (size_t)(m0 + srow) * K + sg;
    const _Float16* Bg = Bm + (size_t)(n0 + srow) * K + sg;
    const int ldst = wave * 512;                     // wave-uniform LDS offset

    // ds_read addressing (halves): granule = (ks*4+quad) ^ (l16&7)
    const int sk = l16 & 7;
    const int g0 = ((0 + quad) ^ sk) << 3;
    const int g1 = ((4 + quad) ^ sk) << 3;
    const int abase = wr * 8192 + l16 * 64;
    const int bbase = wc * 4096 + l16 * 64;

    f32x4_t acc[8][4] = {};

    const int NT    = K >> 6;            // 32 K-tiles
    const int iters = NT >> 1;           // 16 iterations (2 K-tiles each)

    // prologue: tile0 -> buf0, tile1 -> buf1 (16 issues/thread)
    STG_AH(0, 0, 0);  STG_AH(0, 1, 0);  STG_BH(0, 0, 0);  STG_BH(0, 1, 0);
    STG_AH(1, 0, 64); STG_AH(1, 1, 64); STG_BH(1, 0, 64); STG_BH(1, 1, 64);
    asm volatile("s_waitcnt vmcnt(8)" ::: "memory");   // tile0 landed
    BAR;

    for (int i = 0; i < iters; ++i) {
        const int  kb1 = (2 * i + 1) << 6;
        const int  kb2 = (2 * i + 2) << 6;
        const int  kb3 = (2 * i + 3) << 6;
        const bool nx  = (i + 1 < iters);
        half8_t a[4][2], a2[4][2], b[4][2];

        // ---------------- K-tile 2i (buf0) ----------------
        // ph1
        LDA(a, 0, 0);
        LDB(b, 0);
        if (i > 0) STG_AH(1, 1, kb1);     // finish tile 2i+1 (A half1)
        BAR;
        PRIO1; MFMA_Q(a, b, 0, 0); PRIO0;
        BAR;
        // ph2
        LDA(a2, 0, 1);
        if (nx) STG_BH(0, 0, kb2);
        BAR;
        PRIO1; MFMA_Q(a, b, 0, 1); PRIO0;
        BAR;
        // ph3
        if (nx) STG_BH(0, 1, kb2);
        BAR;
        PRIO1; MFMA_Q(a2, b, 1, 1); PRIO0;
        BAR;
        // ph4
        if (nx) STG_AH(0, 0, kb2);
        BAR;
        PRIO1; MFMA_Q(a2, b, 1, 0); PRIO0;
        if (nx) { asm volatile("s_waitcnt vmcnt(6)" ::: "memory"); }
        else    { asm volatile("s_waitcnt vmcnt(0)" ::: "memory"); }
        BAR;                               // tile 2i+1 fully visible

        // ---------------- K-tile 2i+1 (buf1) ----------------
        // ph5
        LDA(a, 1, 0);
        LDB(b, 1);
        if (nx) STG_AH(0, 1, kb2);
        BAR;
        PRIO1; MFMA_Q(a, b, 0, 0); PRIO0;
        BAR;
        // ph6
        LDA(a2, 1, 1);
        if (nx) STG_BH(1, 0, kb3);
        BAR;
        PRIO1; MFMA_Q(a, b, 0, 1); PRIO0;
        BAR;
        // ph7
        if (nx) STG_BH(1, 1, kb3);
        BAR;
        PRIO1; MFMA_Q(a2, b, 1, 1); PRIO0;
        BAR;
        // ph8
        if (nx) STG_AH(1, 0, kb3);
        BAR;
        PRIO1; MFMA_Q(a2, b, 1, 0); PRIO0;
        if (nx) { asm volatile("s_waitcnt vmcnt(6)" ::: "memory"); }
        else    { asm volatile("s_waitcnt vmcnt(0)" ::: "memory"); }
        BAR;                               // tile 2i+2 fully visible
    }

    // ---------------- epilogue ----------------
    // r0 = m0 + wr*128 + mi*16 + quad*4 (+i), c = n0 + wc*64 + ni*16 + l16
    // (C/D layout: col = lane&15, row = (lane>>4)*4 + reg)
    if (QKV && n0 >= 2560) {
        // V -> fragment-packed (formulas identical to harness-verified 128^2 ver.)
#pragma unroll
        for (int ni = 0; ni < 4; ++ni) {
            const int c  = n0 + wc * 64 + ni * 16 + l16;
            const int kd = c - 2560;
            const int kv = kd >> 6, d = kd & 63;
            const int dt = (d >> 4) & 3;
            const float bv = bias[c];
#pragma unroll
            for (int mi = 0; mi < 8; ++mi) {
                const int r0   = m0 + wr * 128 + mi * 16 + quad * 4;
                const int bb   = r0 >> 11;
                const int sblk = (r0 & 2047) >> 6;
                const int nt   = (r0 >> 4) & 3;
                half4_t h;
#pragma unroll
                for (int i = 0; i < 4; ++i) h[i] = (_Float16)(acc[mi][ni][i] + bv);
                *(half4_t*)(vfb + ((size_t)(bb * 8 + kv) * 32 + sblk) * 4096 +
                            ((nt * 4 + dt) * 64 + quad * 16 + (d & 15)) * 4) = h;
            }
        }
    } else if (QKV && n0 >= 2048) {
        // K -> fragment-packed
#pragma unroll
        for (int ni = 0; ni < 4; ++ni) {
            const int c  = n0 + wc * 64 + ni * 16 + l16;
            const int kd = c - 2048;
            const int kv = kd >> 6, d = kd & 63;
            const float bv = bias[c];
#pragma unroll
            for (int mi = 0; mi < 8; ++mi) {
                const int r0   = m0 + wr * 128 + mi * 16 + quad * 4;
                const int bb   = r0 >> 11;
                const int sblk = (r0 & 2047) >> 6;
                const int nt   = (r0 >> 4) & 3;
                _Float16* dst = kfb + ((size_t)(bb * 8 + kv) * 32 + sblk) * 4096 +
                    ((nt * 2 + (d >> 5)) * 64 + ((d >> 3) & 3) * 16 + quad * 4) * 8 +
                    (d & 7);
#pragma unroll
                for (int i = 0; i < 4; ++i)
                    dst[i * 8] = (_Float16)(acc[mi][ni][i] + bv);
            }
        }
    } else {
#pragma unroll
        for (int ni = 0; ni < 4; ++ni) {
            const int c  = n0 + wc * 64 + ni * 16 + l16;
            const float bv = bias[c];
#pragma unroll
            for (int mi = 0; mi < 8; ++mi) {
                const int r0 = m0 + wr * 128 + mi * 16 + quad * 4;
#pragma unroll
                for (int i = 0; i < 4; ++i)
                    C[(size_t)(r0 + i) * ldc + c] = (OutT)(acc[mi][ni][i] + bv);
            }
        }
    }
}

// ---------------------------------------------------------------------------
// GQA flash attention, transposed-score formulation, NO-MAX softmax.
// (unchanged from the harness-verified version)
// ---------------------------------------------------------------------------
__global__ __launch_bounds__(256, 2) void attn_kernel(
    const _Float16* __restrict__ Qb, const _Float16* __restrict__ Kf,
    const _Float16* __restrict__ Vf, _Float16* __restrict__ ctx) {
    __shared__ _Float16 Ks[2][4096];
    __shared__ _Float16 Vs[2][4096];

    const int tid  = threadIdx.x;
    const int wave = tid >> 6;
    const int lane = tid & 63;
    const int quad = lane >> 4;
    const int l16  = lane & 15;
    const int qt  = blockIdx.x;             // 64-row q-tile
    const int bkv = blockIdx.y;
    const int b   = bkv >> 3;
    const int kv  = bkv & 7;
    const int h   = kv * 4 + wave;          // this wave's g-head

    half8_t qa[4][2];
#pragma unroll
    for (int g = 0; g < 4; ++g) {
        const _Float16* qp = Qb + ((size_t)(b * SEQ + qt * 64 + g * 16 + l16)) * HIDDEN
                              + h * 64 + quad * 8;
        qa[g][0] = *(const half8_t*)qp;
        qa[g][1] = *(const half8_t*)(qp + 32);
    }

    f32x4_t ot[4][4] = {};
    f32x4_t lacc[4] = {};
    const half4_t ones = {(_Float16)1.f, (_Float16)1.f, (_Float16)1.f, (_Float16)1.f};

    const size_t kvbase = (size_t)(b * 8 + kv) * 32 * 4096;  // halves
    const int sh = (wave * 2) * 512 + lane * 8;

#pragma unroll
    for (int j = 0; j < 2; ++j) {
        async_copy16(&Ks[0][(wave * 2 + j) * 512], Kf + kvbase + sh + j * 512);
        async_copy16(&Vs[0][(wave * 2 + j) * 512], Vf + kvbase + sh + j * 512);
    }

    for (int kt = 0; kt < SEQ / 64; ++kt) {
        __syncthreads();
        const int cur = kt & 1;
        if (kt + 1 < SEQ / 64) {
            const int nxt = cur ^ 1;
            const size_t off = kvbase + (size_t)(kt + 1) * 4096 + sh;
#pragma unroll
            for (int j = 0; j < 2; ++j) {
                async_copy16(&Ks[nxt][(wave * 2 + j) * 512], Kf + off + j * 512);
                async_copy16(&Vs[nxt][(wave * 2 + j) * 512], Vf + off + j * 512);
            }
        }

        half8_t kf[4][2];
#pragma unroll
        for (int nt = 0; nt < 4; ++nt) {
#pragma unroll
            for (int c = 0; c < 2; ++c)
                kf[nt][c] = *(const half8_t*)(&Ks[cur][((nt * 2 + c) * 64 + lane) * 8]);
        }

        half4_t p[4][4];
#pragma unroll
        for (int g = 0; g < 4; ++g) {
#pragma unroll
            for (int nt = 0; nt < 4; ++nt) {
                f32x4_t s = {};
                s = __builtin_amdgcn_mfma_f32_16x16x32_f16(kf[nt][0], qa[g][0], s, 0, 0, 0);
                s = __builtin_amdgcn_mfma_f32_16x16x32_f16(kf[nt][1], qa[g][1], s, 0, 0, 0);
                const fp16x2_t lo = __builtin_amdgcn_cvt_pkrtz(
                    __builtin_amdgcn_exp2f(s[0]), __builtin_amdgcn_exp2f(s[1]));
                const fp16x2_t hi = __builtin_amdgcn_cvt_pkrtz(
                    __builtin_amdgcn_exp2f(s[2]), __builtin_amdgcn_exp2f(s[3]));
                half4_t pv;
                pv[0] = (_Float16)lo[0]; pv[1] = (_Float16)lo[1];
                pv[2] = (_Float16)hi[0]; pv[3] = (_Float16)hi[1];
                p[g][nt] = pv;
                lacc[g] = __builtin_amdgcn_mfma_f32_16x16x16f16(ones, pv, lacc[g], 0, 0, 0);
            }
        }

#pragma unroll
        for (int nt = 0; nt < 4; ++nt) {
#pragma unroll
            for (int dt = 0; dt < 4; ++dt) {
                const half4_t vf = *(const half4_t*)(&Vs[cur][((nt * 4 + dt) * 64 + lane) * 4]);
#pragma unroll
                for (int g = 0; g < 4; ++g)
                    ot[g][dt] = __builtin_amdgcn_mfma_f32_16x16x16f16(
                        vf, p[g][nt], ot[g][dt], 0, 0, 0);
            }
        }
    }

    __syncthreads();
    _Float16* T = &Ks[0][0] + wave * 1152;
#pragma unroll
    for (int g = 0; g < 4; ++g) {
        const float inv = 1.f / lacc[g][0];
#pragma unroll
        for (int dt = 0; dt < 4; ++dt) {
            half4_t hh;
#pragma unroll
            for (int r = 0; r < 4; ++r) hh[r] = (_Float16)(ot[g][dt][r] * inv);
            *(half4_t*)(T + l16 * 72 + dt * 16 + quad * 4) = hh;
        }
        __builtin_amdgcn_s_waitcnt(0);
        _Float16* cp = ctx + (((size_t)b * 32 + h) * SEQ + qt * 64 + g * 16 + l16) * 64;
#pragma unroll
        for (int pass = 0; pass < 2; ++pass) {
            const half8_t row = *(const half8_t*)(T + l16 * 72 + pass * 32 + quad * 8);
            *(half8_t*)(cp + pass * 32 + quad * 8) = row;
        }
        __builtin_amdgcn_s_waitcnt(0);
    }
}

// ---------------------------------------------------------------------------
// single fused prep kernel: all fp32->fp16 casts + bias packing
// ---------------------------------------------------------------------------
__device__ __forceinline__ void cast4(const float* __restrict__ s,
                                      _Float16* __restrict__ d, int i, float sc) {
    const f32x4_t v = ((const f32x4_t*)s)[i];
    half4_t h;
#pragma unroll
    for (int j = 0; j < 4; ++j) h[j] = (_Float16)(v[j] * sc);
    ((half4_t*)d)[i] = h;
}

__global__ __launch_bounds__(256) void prep(
    const float* __restrict__ X,  const float* __restrict__ Wq,
    const float* __restrict__ Wk, const float* __restrict__ Wv,
    const float* __restrict__ Wo, const float* __restrict__ bq,
    const float* __restrict__ bk, const float* __restrict__ bv,
    _Float16* __restrict__ Xh, _Float16* __restrict__ Wqkv,
    _Float16* __restrict__ Woh, float* __restrict__ bqkv) {
    const int bid = blockIdx.x, tid = threadIdx.x;
    if (bid < 8192)       cast4(X,  Xh,   bid * 256 + tid, 1.f);
    else if (bid < 12288) cast4(Wq, Wqkv, (bid - 8192) * 256 + tid, SCALEQ);
    else if (bid < 13312) cast4(Wk, Wqkv + (size_t)HIDDEN * HIDDEN, (bid - 12288) * 256 + tid, 1.f);
    else if (bid < 14336) cast4(Wv, Wqkv + (size_t)(HIDDEN + 512) * HIDDEN, (bid - 13312) * 256 + tid, 1.f);
    else if (bid < 18432) cast4(Wo, Woh,  (bid - 14336) * 256 + tid, 1.f);
    else {
        const int i = (bid - 18432) * 256 + tid;
        if (i < 2048)      bqkv[i] = bq[i] * SCALEQ;
        else if (i < 2560) bqkv[i] = bk[i - 2048];
        else if (i < 3072) bqkv[i] = bv[i - 2560];
    }
}

// ---------------------------------------------------------------------------
extern "C" void kernel_launch(void* const* d_in, const int* in_sizes, int n_in,
                              void* d_out, int out_size, void* d_ws, size_t ws_size,
                              hipStream_t stream) {
    const float* X  = (const float*)d_in[0];
    const float* Wq = (const float*)d_in[1];
    const float* bq = (const float*)d_in[2];
    const float* Wk = (const float*)d_in[3];
    const float* bk = (const float*)d_in[4];
    const float* Wv = (const float*)d_in[5];
    const float* bv = (const float*)d_in[6];
    const float* Wo = (const float*)d_in[7];
    const float* bo = (const float*)d_in[8];
    float* out = (float*)d_out;

    char* p = (char*)d_ws;
    _Float16* Xh   = (_Float16*)p; p += (size_t)MROWS * HIDDEN * 2;   // 16.8 MB (reused as ctx)
    _Float16* Wqkv = (_Float16*)p; p += (size_t)NQKV * HIDDEN * 2;    // 12.6 MB
    _Float16* Woh  = (_Float16*)p; p += (size_t)HIDDEN * HIDDEN * 2;  //  8.4 MB
    float*    bqkv = (float*)p;    p += (size_t)NQKV * 4;
    _Float16* Qb   = (_Float16*)p; p += (size_t)MROWS * HIDDEN * 2;   // 16.8 MB
    _Float16* Kfb  = (_Float16*)p; p += (size_t)16 * 32 * 4096 * 2;   //  4.2 MB frag-packed
    _Float16* Vfb  = (_Float16*)p; p += (size_t)16 * 32 * 4096 * 2;   //  4.2 MB frag-packed
    _Float16* ctx  = Xh;  // alias: Xh dead after QKV GEMM

    prep<<<18444, 256, 0, stream>>>(X, Wq, Wk, Wv, Wo, bq, bk, bv,
                                    Xh, Wqkv, Woh, bqkv);

    // QKV projection: Q -> Qb row-major; K,V -> fragment-packed blocks
    gemm256<_Float16, true><<<dim3(NQKV / 256, MROWS / 256), 512, 0, stream>>>(
        Xh, Wqkv, bqkv, Qb, Kfb, Vfb, HIDDEN, HIDDEN);

    // attention -> ctx [b][h][s][d] fp16
    attn_kernel<<<dim3(SEQ / 64, BATCH * NKV), 256, 0, stream>>>(Qb, Kfb, Vfb, ctx);

    // output projection: ctx [4096 x 2048] x Wo^T + bo -> fp32 d_out
    gemm256<float, false><<<dim3(HIDDEN / 256, MROWS / 256), 512, 0, stream>>>(
        ctx, Woh, bo, out, nullptr, nullptr, HIDDEN, HIDDEN);
}

// Round 2
// 320.920 us; speedup vs baseline: 1.0844x; 1.0844x over previous
//
#include <hip/hip_runtime.h>

#define HIDDEN 2048
#define NHEADS 32
#define NKV    8
#define HDIM   64
#define BATCH  2
#define SEQ    2048
#define MROWS  (BATCH*SEQ)          // 4096
#define NQKV   3072                 // 2048 Q + 512 K + 512 V

// scale 1/sqrt(64) * log2(e): folded into Wq/bq so softmax uses native exp2
#define SCALEQ 0.18033688011112042f

typedef _Float16 half8_t __attribute__((ext_vector_type(8)));
typedef _Float16 half4_t __attribute__((ext_vector_type(4)));
typedef __fp16   fp16x2_t __attribute__((ext_vector_type(2)));
typedef float    f32x4_t __attribute__((ext_vector_type(4)));

#define AS1 __attribute__((address_space(1)))
#define AS3 __attribute__((address_space(3)))

__device__ __forceinline__ void async_copy16(void* lds, const void* g) {
    // LDS dest = wave-uniform base + lane*16 (m104/m108)
    __builtin_amdgcn_global_load_lds((AS1 void*)g, (AS3 void*)lds, 16, 0, 0);
}

#define PRIO1 __builtin_amdgcn_s_setprio(1)
#define PRIO0 __builtin_amdgcn_s_setprio(0)
#define BAR   __builtin_amdgcn_s_barrier()

// ---------------------------------------------------------------------------
// 128x256 8-phase-style NT GEMM. 8 waves (512 thr): wave (wr,wc)=(w>>2,w&3)
// owns a 64x64 output tile -> acc[4][4] = 64 VGPR (half of the 256^2 version;
// total ~150 VGPR, far from the 256 spill cliff that likely capped round 1).
// BK=64; LDS = 2dbuf x (A 128x64 + B 256x64) fp16 = 96 KiB -> 1 block/CU.
// Per K-tile: 2 fat phases of 16 MFMA each (m201 granularity):
//   ph1: ds-read aL(4 b128) + b(8 b128); stage A(t+1) -> OTHER buffer (2 units)
//        BAR; MFMA aL x b (16); BAR
//   ph2: ds-read aH(4); stage B(t+2) -> current buffer (4 units; B-reads all
//        completed before ph1-end barrier -> race-free); BAR; MFMA aH x b (16);
//        vmcnt(4); BAR   [leaves exactly this tile's 4 B-issues in flight;
//        completes A(t+1)+B(t+1) -> next tile fully visible]
// Swizzle (both-sides, rule 21): logical granule g of row r stored at slot
// g ^ (r&7); source address pre-swizzled, ds_read applies same XOR.
// Stage unit = 64 rows x 64 halves = 1 global_load_lds(16B)/thread.
// ---------------------------------------------------------------------------

#define STG_A(bi, u, kb) \
    async_copy16(&As[bi][(u)*4096 + ldst], Ag + (size_t)((u)*64) * K + (kb))
#define STG_B(bi, u, kb) \
    async_copy16(&Bs[bi][(u)*4096 + ldst], Bg + (size_t)((u)*64) * K + (kb))

#define LDA2(dst, bi, mh) do {                                                 \
    _Pragma("unroll") for (int mi = 0; mi < 2; ++mi) {                         \
        dst[mi][0] = *(const half8_t*)(&As[bi][abase + ((mh)*2+mi)*1024 + g0]);\
        dst[mi][1] = *(const half8_t*)(&As[bi][abase + ((mh)*2+mi)*1024 + g1]);\
    } } while (0)

#define LDB4(dst, bi) do {                                                     \
    _Pragma("unroll") for (int ni = 0; ni < 4; ++ni) {                         \
        dst[ni][0] = *(const half8_t*)(&Bs[bi][bbase + ni*1024 + g0]);         \
        dst[ni][1] = *(const half8_t*)(&Bs[bi][bbase + ni*1024 + g1]);         \
    } } while (0)

#define MFMA_H(av, mh) do {                                                    \
    _Pragma("unroll") for (int mi = 0; mi < 2; ++mi)                           \
    _Pragma("unroll") for (int ni = 0; ni < 4; ++ni) {                         \
        f32x4_t& cc = acc[(mh)*2 + mi][ni];                                    \
        cc = __builtin_amdgcn_mfma_f32_16x16x32_f16(av[mi][0], b[ni][0], cc, 0, 0, 0); \
        cc = __builtin_amdgcn_mfma_f32_16x16x32_f16(av[mi][1], b[ni][1], cc, 0, 0, 0); \
    } } while (0)

template <typename OutT, bool QKV>
__global__ __launch_bounds__(512, 2) void gemm128(
    const _Float16* __restrict__ A, const _Float16* __restrict__ Bm,
    const float* __restrict__ bias, OutT* __restrict__ C,
    _Float16* __restrict__ kfb, _Float16* __restrict__ vfb,
    int K, int ldc) {
    __shared__ _Float16 As[2][8192];    // 128 x 64 per buf
    __shared__ _Float16 Bs[2][16384];   // 256 x 64 per buf

    const int tid  = threadIdx.x;
    const int wave = tid >> 6;
    const int lane = tid & 63;
    const int quad = lane >> 4;
    const int l16  = lane & 15;
    const int wr   = wave >> 2;          // 0..1 : 64-row half
    const int wc   = wave & 3;           // 0..3 : 64-col quarter

    // bijective XCD swizzle (nwg % 8 == 0 at both call sites: 384, 256)
    const int nwg = (int)(gridDim.x * gridDim.y);
    const int lin = (int)(blockIdx.y * gridDim.x + blockIdx.x);
    const int q8  = nwg >> 3;
    const int idx = (lin & 7) * q8 + (lin >> 3);
    const int tx  = idx % (int)gridDim.x;
    const int ty  = idx / (int)gridDim.x;
    const int m0  = ty * 128;
    const int n0  = tx * 256;

    // staging: thread t covers (row = t>>3, granule-slot = t&7) of a 64-row
    // unit; source granule pre-swizzled by row&7.
    const int srow = tid >> 3;                       // 0..63
    const int sg   = ((tid & 7) ^ (srow & 7)) << 3;  // halves
    const _Float16* Ag = A  + (size_t)(m0 + srow) * K + sg;
    const _Float16* Bg = Bm + (size_t)(n0 + srow) * K + sg;
    const int ldst = wave * 512;                     // wave-uniform LDS offset

    // ds_read addressing (halves): slot = (c*4+quad) ^ (l16&7)
    const int sk = l16 & 7;
    const int g0 = ((0 + quad) ^ sk) << 3;
    const int g1 = ((4 + quad) ^ sk) << 3;
    const int abase = wr * 4096 + l16 * 64;          // + mi*1024 + g
    const int bbase = wc * 4096 + l16 * 64;          // + ni*1024 + g

    f32x4_t acc[4][4] = {};
    const int NT = K >> 6;               // 32 K-tiles

    // prologue: tile0 fully (A 2 + B 4), tile1 B only (A(t1) staged at t0 ph1)
    STG_A(0, 0, 0);  STG_A(0, 1, 0);
    STG_B(0, 0, 0);  STG_B(0, 1, 0);  STG_B(0, 2, 0);  STG_B(0, 3, 0);
    STG_B(1, 0, 64); STG_B(1, 1, 64); STG_B(1, 2, 64); STG_B(1, 3, 64);
    asm volatile("s_waitcnt vmcnt(4)" ::: "memory");   // tile0 landed
    BAR;

    for (int t = 0; t < NT; ++t) {
        const int  cur = t & 1;
        const int  kA  = (t + 1) << 6;
        const int  kB  = (t + 2) << 6;
        const bool sA  = (t + 1 < NT);
        const bool sB  = (t + 2 < NT);
        half8_t aL[2][2], aH[2][2], b[4][2];

        // ph1
        LDA2(aL, cur, 0);
        LDB4(b, cur);
        if (sA) { STG_A(cur ^ 1, 0, kA); STG_A(cur ^ 1, 1, kA); }
        BAR;
        PRIO1; MFMA_H(aL, 0); PRIO0;
        BAR;
        // ph2
        LDA2(aH, cur, 1);
        if (sB) { STG_B(cur, 0, kB); STG_B(cur, 1, kB);
                  STG_B(cur, 2, kB); STG_B(cur, 3, kB); }
        BAR;
        PRIO1; MFMA_H(aH, 1); PRIO0;
        if (sB) { asm volatile("s_waitcnt vmcnt(4)" ::: "memory"); }
        else    { asm volatile("s_waitcnt vmcnt(0)" ::: "memory"); }
        BAR;                               // tile t+1 fully visible
    }

    // ---------------- epilogue ----------------
    // r0 = m0 + wr*64 + mi*16 + quad*4 (+i), c = n0 + wc*64 + ni*16 + l16
    if (QKV && n0 >= 2560) {
        // V -> fragment-packed (harness-verified formulas; depend only on r0,c)
#pragma unroll
        for (int ni = 0; ni < 4; ++ni) {
            const int c  = n0 + wc * 64 + ni * 16 + l16;
            const int kd = c - 2560;
            const int kv = kd >> 6, d = kd & 63;
            const int dt = (d >> 4) & 3;
            const float bv = bias[c];
#pragma unroll
            for (int mi = 0; mi < 4; ++mi) {
                const int r0   = m0 + wr * 64 + mi * 16 + quad * 4;
                const int bb   = r0 >> 11;
                const int sblk = (r0 & 2047) >> 6;
                const int nt   = (r0 >> 4) & 3;
                half4_t h;
#pragma unroll
                for (int i = 0; i < 4; ++i) h[i] = (_Float16)(acc[mi][ni][i] + bv);
                *(half4_t*)(vfb + ((size_t)(bb * 8 + kv) * 32 + sblk) * 4096 +
                            ((nt * 4 + dt) * 64 + quad * 16 + (d & 15)) * 4) = h;
            }
        }
    } else if (QKV && n0 >= 2048) {
        // K -> fragment-packed
#pragma unroll
        for (int ni = 0; ni < 4; ++ni) {
            const int c  = n0 + wc * 64 + ni * 16 + l16;
            const int kd = c - 2048;
            const int kv = kd >> 6, d = kd & 63;
            const float bv = bias[c];
#pragma unroll
            for (int mi = 0; mi < 4; ++mi) {
                const int r0   = m0 + wr * 64 + mi * 16 + quad * 4;
                const int bb   = r0 >> 11;
                const int sblk = (r0 & 2047) >> 6;
                const int nt   = (r0 >> 4) & 3;
                _Float16* dst = kfb + ((size_t)(bb * 8 + kv) * 32 + sblk) * 4096 +
                    ((nt * 2 + (d >> 5)) * 64 + ((d >> 3) & 3) * 16 + quad * 4) * 8 +
                    (d & 7);
#pragma unroll
                for (int i = 0; i < 4; ++i)
                    dst[i * 8] = (_Float16)(acc[mi][ni][i] + bv);
            }
        }
    } else {
#pragma unroll
        for (int ni = 0; ni < 4; ++ni) {
            const int c  = n0 + wc * 64 + ni * 16 + l16;
            const float bv = bias[c];
#pragma unroll
            for (int mi = 0; mi < 4; ++mi) {
                const int r0 = m0 + wr * 64 + mi * 16 + quad * 4;
#pragma unroll
                for (int i = 0; i < 4; ++i)
                    C[(size_t)(r0 + i) * ldc + c] = (OutT)(acc[mi][ni][i] + bv);
            }
        }
    }
}

// ---------------------------------------------------------------------------
// GQA flash attention, transposed-score, NO-MAX softmax (ones-trick row sums).
// RESTRUCTURED: 512 threads = 8 waves = 4 g-heads x 2 q-halves (32 rows each).
// Grid unchanged (512 blocks) -> 2 blocks/CU -> 16 waves/CU = 4 waves/SIMD
// (was 2/SIMD): doubles the TLP hiding the QK->exp2->PV serial chain.
// QK and PV fused per nt-subtile to keep the live set ~90 VGPR so
// __launch_bounds__(512,4) holds without spills (<=128 VGPR needed).
// KV staged once per block, shared by all 8 waves (1 K + 1 V issue/wave).
// ---------------------------------------------------------------------------
__global__ __launch_bounds__(512, 4) void attn_kernel(
    const _Float16* __restrict__ Qb, const _Float16* __restrict__ Kf,
    const _Float16* __restrict__ Vf, _Float16* __restrict__ ctx) {
    __shared__ _Float16 S[16384];   // [0,8192): K dbuf | [8192,16384): V dbuf

    const int tid  = threadIdx.x;
    const int wave = tid >> 6;
    const int lane = tid & 63;
    const int quad = lane >> 4;
    const int l16  = lane & 15;
    const int qs   = wave >> 2;             // 0..1 : q-half (32 rows)
    const int wh   = wave & 3;              // 0..3 : g-head
    const int qt  = blockIdx.x;             // 64-row q-tile
    const int bkv = blockIdx.y;
    const int b   = bkv >> 3;
    const int kv  = bkv & 7;
    const int h   = kv * 4 + wh;

    // Q fragments for this wave's 2 q-groups
    half8_t qa[2][2];
#pragma unroll
    for (int g = 0; g < 2; ++g) {
        const _Float16* qp = Qb +
            ((size_t)(b * SEQ + qt * 64 + qs * 32 + g * 16 + l16)) * HIDDEN +
            h * 64 + quad * 8;
        qa[g][0] = *(const half8_t*)qp;
        qa[g][1] = *(const half8_t*)(qp + 32);
    }

    f32x4_t ot[2][4] = {};                  // O^T accum per group
    f32x4_t lacc[2] = {};                   // row-sum accum (ones-trick)
    const half4_t ones = {(_Float16)1.f, (_Float16)1.f, (_Float16)1.f, (_Float16)1.f};

    const size_t kvbase = (size_t)(b * 8 + kv) * 32 * 4096;  // halves
    const int sh = wave * 512 + lane * 8;   // this wave's staging slice

    // prologue: tile 0 -> buf 0 (1 K-issue + 1 V-issue per wave)
    async_copy16(&S[wave * 512],        Kf + kvbase + sh);
    async_copy16(&S[8192 + wave * 512], Vf + kvbase + sh);

    for (int kt = 0; kt < SEQ / 64; ++kt) {
        __syncthreads();                     // drains tile kt's async copies
        const int cur = kt & 1;
        if (kt + 1 < SEQ / 64) {
            const size_t off = kvbase + (size_t)(kt + 1) * 4096 + sh;
            async_copy16(&S[(cur ^ 1) * 4096 + wave * 512],        Kf + off);
            async_copy16(&S[8192 + (cur ^ 1) * 4096 + wave * 512], Vf + off);
        }
        const int kb = cur * 4096, vb = 8192 + cur * 4096;

#pragma unroll
        for (int nt = 0; nt < 4; ++nt) {
            const half8_t kf0 = *(const half8_t*)(&S[kb + ((nt * 2 + 0) * 64 + lane) * 8]);
            const half8_t kf1 = *(const half8_t*)(&S[kb + ((nt * 2 + 1) * 64 + lane) * 8]);
            half4_t p[2];
#pragma unroll
            for (int g = 0; g < 2; ++g) {
                f32x4_t s = {};
                s = __builtin_amdgcn_mfma_f32_16x16x32_f16(kf0, qa[g][0], s, 0, 0, 0);
                s = __builtin_amdgcn_mfma_f32_16x16x32_f16(kf1, qa[g][1], s, 0, 0, 0);
                const fp16x2_t lo = __builtin_amdgcn_cvt_pkrtz(
                    __builtin_amdgcn_exp2f(s[0]), __builtin_amdgcn_exp2f(s[1]));
                const fp16x2_t hi = __builtin_amdgcn_cvt_pkrtz(
                    __builtin_amdgcn_exp2f(s[2]), __builtin_amdgcn_exp2f(s[3]));
                half4_t pv;
                pv[0] = (_Float16)lo[0]; pv[1] = (_Float16)lo[1];
                pv[2] = (_Float16)hi[0]; pv[3] = (_Float16)hi[1];
                p[g] = pv;
                lacc[g] = __builtin_amdgcn_mfma_f32_16x16x16f16(ones, pv, lacc[g], 0, 0, 0);
            }
#pragma unroll
            for (int dt = 0; dt < 4; ++dt) {
                const half4_t vf = *(const half4_t*)(&S[vb + ((nt * 4 + dt) * 64 + lane) * 4]);
                ot[0][dt] = __builtin_amdgcn_mfma_f32_16x16x16f16(vf, p[0], ot[0][dt], 0, 0, 0);
                ot[1][dt] = __builtin_amdgcn_mfma_f32_16x16x16f16(vf, p[1], ot[1][dt], 0, 0, 0);
            }
        }
    }

    // epilogue: O^T -> O via per-wave LDS transpose, coalesced ctx writes.
    __syncthreads();                         // KV buffers dead
    _Float16* T = S + wave * 1152;           // 16 rows x 72 (pad vs bank clash)
#pragma unroll
    for (int g = 0; g < 2; ++g) {
        const float inv = 1.f / lacc[g][0];  // full row sum (ones-trick)
#pragma unroll
        for (int dt = 0; dt < 4; ++dt) {
            half4_t hh;
#pragma unroll
            for (int r = 0; r < 4; ++r) hh[r] = (_Float16)(ot[g][dt][r] * inv);
            *(half4_t*)(T + l16 * 72 + dt * 16 + quad * 4) = hh;
        }
        __builtin_amdgcn_s_waitcnt(0);       // lgkm drain: wave-internal LDS RAW
        _Float16* cp = ctx +
            (((size_t)b * 32 + h) * SEQ + qt * 64 + qs * 32 + g * 16 + l16) * 64;
#pragma unroll
        for (int pass = 0; pass < 2; ++pass) {
            const half8_t row = *(const half8_t*)(T + l16 * 72 + pass * 32 + quad * 8);
            *(half8_t*)(cp + pass * 32 + quad * 8) = row;
        }
        __builtin_amdgcn_s_waitcnt(0);       // before next group overwrites T
    }
}

// ---------------------------------------------------------------------------
// single fused prep kernel: all fp32->fp16 casts + bias packing
// ---------------------------------------------------------------------------
__device__ __forceinline__ void cast4(const float* __restrict__ s,
                                      _Float16* __restrict__ d, int i, float sc) {
    const f32x4_t v = ((const f32x4_t*)s)[i];
    half4_t h;
#pragma unroll
    for (int j = 0; j < 4; ++j) h[j] = (_Float16)(v[j] * sc);
    ((half4_t*)d)[i] = h;
}

__global__ __launch_bounds__(256) void prep(
    const float* __restrict__ X,  const float* __restrict__ Wq,
    const float* __restrict__ Wk, const float* __restrict__ Wv,
    const float* __restrict__ Wo, const float* __restrict__ bq,
    const float* __restrict__ bk, const float* __restrict__ bv,
    _Float16* __restrict__ Xh, _Float16* __restrict__ Wqkv,
    _Float16* __restrict__ Woh, float* __restrict__ bqkv) {
    const int bid = blockIdx.x, tid = threadIdx.x;
    if (bid < 8192)       cast4(X,  Xh,   bid * 256 + tid, 1.f);
    else if (bid < 12288) cast4(Wq, Wqkv, (bid - 8192) * 256 + tid, SCALEQ);
    else if (bid < 13312) cast4(Wk, Wqkv + (size_t)HIDDEN * HIDDEN, (bid - 12288) * 256 + tid, 1.f);
    else if (bid < 14336) cast4(Wv, Wqkv + (size_t)(HIDDEN + 512) * HIDDEN, (bid - 13312) * 256 + tid, 1.f);
    else if (bid < 18432) cast4(Wo, Woh,  (bid - 14336) * 256 + tid, 1.f);
    else {
        const int i = (bid - 18432) * 256 + tid;
        if (i < 2048)      bqkv[i] = bq[i] * SCALEQ;
        else if (i < 2560) bqkv[i] = bk[i - 2048];
        else if (i < 3072) bqkv[i] = bv[i - 2560];
    }
}

// ---------------------------------------------------------------------------
extern "C" void kernel_launch(void* const* d_in, const int* in_sizes, int n_in,
                              void* d_out, int out_size, void* d_ws, size_t ws_size,
                              hipStream_t stream) {
    const float* X  = (const float*)d_in[0];
    const float* Wq = (const float*)d_in[1];
    const float* bq = (const float*)d_in[2];
    const float* Wk = (const float*)d_in[3];
    const float* bk = (const float*)d_in[4];
    const float* Wv = (const float*)d_in[5];
    const float* bv = (const float*)d_in[6];
    const float* Wo = (const float*)d_in[7];
    const float* bo = (const float*)d_in[8];
    float* out = (float*)d_out;

    char* p = (char*)d_ws;
    _Float16* Xh   = (_Float16*)p; p += (size_t)MROWS * HIDDEN * 2;   // 16.8 MB (reused as ctx)
    _Float16* Wqkv = (_Float16*)p; p += (size_t)NQKV * HIDDEN * 2;    // 12.6 MB
    _Float16* Woh  = (_Float16*)p; p += (size_t)HIDDEN * HIDDEN * 2;  //  8.4 MB
    float*    bqkv = (float*)p;    p += (size_t)NQKV * 4;
    _Float16* Qb   = (_Float16*)p; p += (size_t)MROWS * HIDDEN * 2;   // 16.8 MB
    _Float16* Kfb  = (_Float16*)p; p += (size_t)16 * 32 * 4096 * 2;   //  4.2 MB frag-packed
    _Float16* Vfb  = (_Float16*)p; p += (size_t)16 * 32 * 4096 * 2;   //  4.2 MB frag-packed
    _Float16* ctx  = Xh;  // alias: Xh dead after QKV GEMM

    prep<<<18444, 256, 0, stream>>>(X, Wq, Wk, Wv, Wo, bq, bk, bv,
                                    Xh, Wqkv, Woh, bqkv);

    // QKV projection: Q -> Qb row-major; K,V -> fragment-packed blocks
    // grid 12x32 = 384 blocks (%8==0 for XCD swizzle)
    gemm128<_Float16, true><<<dim3(NQKV / 256, MROWS / 128), 512, 0, stream>>>(
        Xh, Wqkv, bqkv, Qb, Kfb, Vfb, HIDDEN, HIDDEN);

    // attention -> ctx [b][h][s][d] fp16 (512 blocks x 512 thr)
    attn_kernel<<<dim3(SEQ / 64, BATCH * NKV), 512, 0, stream>>>(Qb, Kfb, Vfb, ctx);

    // output projection: grid 8x32 = 256 blocks -> exact machine fill
    gemm128<float, false><<<dim3(HIDDEN / 256, MROWS / 128), 512, 0, stream>>>(
        ctx, Woh, bo, out, nullptr, nullptr, HIDDEN, HIDDEN);
}

// Round 3
// 311.455 us; speedup vs baseline: 1.1173x; 1.0304x over previous
//
#include <hip/hip_runtime.h>

#define HIDDEN 2048
#define NHEADS 32
#define NKV    8
#define HDIM   64
#define BATCH  2
#define SEQ    2048
#define MROWS  (BATCH*SEQ)          // 4096
#define NQKV   3072                 // 2048 Q + 512 K + 512 V

// scale 1/sqrt(64) * log2(e): folded into Wq/bq so softmax uses native exp2
#define SCALEQ 0.18033688011112042f

typedef _Float16 half8_t __attribute__((ext_vector_type(8)));
typedef _Float16 half4_t __attribute__((ext_vector_type(4)));
typedef __fp16   fp16x2_t __attribute__((ext_vector_type(2)));
typedef float    f32x4_t __attribute__((ext_vector_type(4)));

#define AS1 __attribute__((address_space(1)))
#define AS3 __attribute__((address_space(3)))

__device__ __forceinline__ void async_copy16(void* lds, const void* g) {
    // LDS dest = wave-uniform base + lane*16 (m104/m108)
    __builtin_amdgcn_global_load_lds((AS1 void*)g, (AS3 void*)lds, 16, 0, 0);
}

#define PRIO1 __builtin_amdgcn_s_setprio(1)
#define PRIO0 __builtin_amdgcn_s_setprio(0)
#define BAR   __builtin_amdgcn_s_barrier()

// ---------------------------------------------------------------------------
// QKV GEMM: 128x192 tile, BK=64, 8 waves (512 thr), 2 blocks/CU (80 KB LDS).
// Grid 16x32 = 512 blocks = exactly 2/CU -> 100% machine fill, 4 waves/SIMD.
// Wave (wr,wc) = (w>>2, w&3) owns 64x48 (acc[4][3] = 48 VGPR).
// Per K-tile, 2 phases (12 MFMA each), counted vmcnt(3):
//   ph1: ds aL(4 b128)+b(6 b128); stage A(t+1)->other buf (2 units); BAR;
//        MFMA aLxb; BAR
//   ph2: ds aH(4); stage B(t+2)->cur buf (3 units; cur-B reads all retired
//        before ph1-end BAR -> race-free); BAR; MFMA aHxb; vmcnt(3); BAR
//        [drains A(t+1),B(t+1); leaves B(t+2) x3 in flight]
// Swizzle (both-sides, rule 21): granule g of row r at slot g ^ (r&7);
// source pre-swizzled, ds_read applies same XOR -> conflict-free b128.
// Epilogue: 192-col tiles straddle the Q/K/V boundaries (2048, 2560) ->
// branch per 16-col group on wave-uniform cbase. K/V fragment-pack formulas
// depend only on absolute (r0, c) + quad/l16. V-pack uses the PAIRED layout
// (dt even/odd contiguous) so attention reads V as conflict-free b128.
// ---------------------------------------------------------------------------

#define QSTG_A(bi, u, kb) \
    async_copy16(&As[bi][(u)*4096 + ldst], Ag + (size_t)((u)*64) * 2048 + (kb))
#define QSTG_B(bi, u, kb) \
    async_copy16(&Bs[bi][(u)*4096 + ldst], Bg + (size_t)((u)*64) * 2048 + (kb))

__global__ __launch_bounds__(512, 4) void gemm_qkv(
    const _Float16* __restrict__ A, const _Float16* __restrict__ Bm,
    const float* __restrict__ bias, _Float16* __restrict__ Qb,
    _Float16* __restrict__ kfb, _Float16* __restrict__ vfb) {
    __shared__ _Float16 As[2][8192];    // 128 x 64 per buf (32 KB)
    __shared__ _Float16 Bs[2][12288];   // 192 x 64 per buf (48 KB)

    const int tid  = threadIdx.x;
    const int wave = tid >> 6;
    const int lane = tid & 63;
    const int quad = lane >> 4;
    const int l16  = lane & 15;
    const int wr   = wave >> 2;          // 0..1 : 64-row half
    const int wc   = wave & 3;           // 0..3 : 48-col slice

    // bijective XCD swizzle (nwg = 512, %8 == 0)
    const int lin = (int)(blockIdx.y * gridDim.x + blockIdx.x);
    const int idx = (lin & 7) * 64 + (lin >> 3);
    const int m0  = (idx >> 4) * 128;    // idx/16 : 32 row-tiles
    const int n0  = (idx & 15) * 192;    // idx%16 : 16 col-tiles

    const int srow = tid >> 3;                       // 0..63
    const int sg   = ((tid & 7) ^ (srow & 7)) << 3;  // pre-swizzled granule
    const _Float16* Ag = A  + (size_t)(m0 + srow) * 2048 + sg;
    const _Float16* Bg = Bm + (size_t)(n0 + srow) * 2048 + sg;
    const int ldst = wave * 512;

    const int sk = l16 & 7;
    const int g0 = ((0 + quad) ^ sk) << 3;
    const int g1 = ((4 + quad) ^ sk) << 3;
    const int abase = wr * 4096 + l16 * 64;          // + mi*1024 + g
    const int bbase = wc * 3072 + l16 * 64;          // + ni*1024 + g

    f32x4_t acc[4][3] = {};

    // prologue: tile0 (A2+B3) -> buf0, tile1 B3 -> buf1
    QSTG_A(0, 0, 0);  QSTG_A(0, 1, 0);
    QSTG_B(0, 0, 0);  QSTG_B(0, 1, 0);  QSTG_B(0, 2, 0);
    QSTG_B(1, 0, 64); QSTG_B(1, 1, 64); QSTG_B(1, 2, 64);
    asm volatile("s_waitcnt vmcnt(3)" ::: "memory");   // tile0 landed
    BAR;

    for (int t = 0; t < 32; ++t) {
        const int  cur = t & 1;
        const int  kA  = (t + 1) << 6;
        const int  kB  = (t + 2) << 6;
        const bool sA  = (t + 1 < 32);
        const bool sB  = (t + 2 < 32);
        half8_t a[2][2], b[3][2];

        // ph1
#pragma unroll
        for (int mi = 0; mi < 2; ++mi) {
            a[mi][0] = *(const half8_t*)(&As[cur][abase + mi * 1024 + g0]);
            a[mi][1] = *(const half8_t*)(&As[cur][abase + mi * 1024 + g1]);
        }
#pragma unroll
        for (int ni = 0; ni < 3; ++ni) {
            b[ni][0] = *(const half8_t*)(&Bs[cur][bbase + ni * 1024 + g0]);
            b[ni][1] = *(const half8_t*)(&Bs[cur][bbase + ni * 1024 + g1]);
        }
        if (sA) { QSTG_A(cur ^ 1, 0, kA); QSTG_A(cur ^ 1, 1, kA); }
        BAR;
        PRIO1;
#pragma unroll
        for (int mi = 0; mi < 2; ++mi)
#pragma unroll
            for (int ni = 0; ni < 3; ++ni) {
                acc[mi][ni] = __builtin_amdgcn_mfma_f32_16x16x32_f16(a[mi][0], b[ni][0], acc[mi][ni], 0, 0, 0);
                acc[mi][ni] = __builtin_amdgcn_mfma_f32_16x16x32_f16(a[mi][1], b[ni][1], acc[mi][ni], 0, 0, 0);
            }
        PRIO0;
        BAR;
        // ph2
#pragma unroll
        for (int mi = 0; mi < 2; ++mi) {
            a[mi][0] = *(const half8_t*)(&As[cur][abase + (2 + mi) * 1024 + g0]);
            a[mi][1] = *(const half8_t*)(&As[cur][abase + (2 + mi) * 1024 + g1]);
        }
        if (sB) { QSTG_B(cur, 0, kB); QSTG_B(cur, 1, kB); QSTG_B(cur, 2, kB); }
        BAR;
        PRIO1;
#pragma unroll
        for (int mi = 0; mi < 2; ++mi)
#pragma unroll
            for (int ni = 0; ni < 3; ++ni) {
                acc[2 + mi][ni] = __builtin_amdgcn_mfma_f32_16x16x32_f16(a[mi][0], b[ni][0], acc[2 + mi][ni], 0, 0, 0);
                acc[2 + mi][ni] = __builtin_amdgcn_mfma_f32_16x16x32_f16(a[mi][1], b[ni][1], acc[2 + mi][ni], 0, 0, 0);
            }
        PRIO0;
        if (sB) { asm volatile("s_waitcnt vmcnt(3)" ::: "memory"); }
        else    { asm volatile("s_waitcnt vmcnt(0)" ::: "memory"); }
        BAR;                               // tile t+1 fully visible
    }

    // epilogue: r0 = m0 + wr*64 + mi*16 + quad*4 (+i), c = cbase + l16
#pragma unroll
    for (int ni = 0; ni < 3; ++ni) {
        const int cbase = n0 + wc * 48 + ni * 16;    // wave-uniform (16-aligned)
        const int c  = cbase + l16;
        const float bv = bias[c];
        if (cbase < 2048) {
            // Q -> row-major
#pragma unroll
            for (int mi = 0; mi < 4; ++mi) {
                const int r0 = m0 + wr * 64 + mi * 16 + quad * 4;
#pragma unroll
                for (int i = 0; i < 4; ++i)
                    Qb[(size_t)(r0 + i) * HIDDEN + c] = (_Float16)(acc[mi][ni][i] + bv);
            }
        } else if (cbase < 2560) {
            // K -> fragment-packed (harness-verified formulas)
            const int kd = c - 2048;
            const int kvh = kd >> 6, d = kd & 63;
#pragma unroll
            for (int mi = 0; mi < 4; ++mi) {
                const int r0   = m0 + wr * 64 + mi * 16 + quad * 4;
                const int bb   = r0 >> 11;
                const int sblk = (r0 & 2047) >> 6;
                const int nt   = (r0 >> 4) & 3;
                _Float16* dst = kfb + ((size_t)(bb * 8 + kvh) * 32 + sblk) * 4096 +
                    ((nt * 2 + (d >> 5)) * 64 + ((d >> 3) & 3) * 16 + quad * 4) * 8 +
                    (d & 7);
#pragma unroll
                for (int i = 0; i < 4; ++i)
                    dst[i * 8] = (_Float16)(acc[mi][ni][i] + bv);
            }
        } else {
            // V -> PAIRED fragment-pack: block (nt,dtp) of 512 halves =
            // [quad(k-mid)][d&15][dt&1][k-lo]; attn reads b128 per (nt,dtp).
            const int kd = c - 2560;
            const int kvh = kd >> 6, d = kd & 63;
            const int dt = (d >> 4) & 3;
#pragma unroll
            for (int mi = 0; mi < 4; ++mi) {
                const int r0   = m0 + wr * 64 + mi * 16 + quad * 4;
                const int bb   = r0 >> 11;
                const int sblk = (r0 & 2047) >> 6;
                const int nt   = (r0 >> 4) & 3;
                half4_t h;
#pragma unroll
                for (int i = 0; i < 4; ++i) h[i] = (_Float16)(acc[mi][ni][i] + bv);
                *(half4_t*)(vfb + ((size_t)(bb * 8 + kvh) * 32 + sblk) * 4096 +
                            (nt * 2 + (dt >> 1)) * 512 + quad * 128 +
                            (d & 15) * 8 + (dt & 1) * 4) = h;
            }
        }
    }
}

// ---------------------------------------------------------------------------
// Output projection: 128x256 tile, BK=64, 8 waves, 96 KB LDS, 1 block/CU.
// Grid 8x32 = 256 blocks = exact machine fill. (Round-2 structure, verified.)
// ---------------------------------------------------------------------------
#define OSTG_A(bi, u, kb) \
    async_copy16(&As[bi][(u)*4096 + ldst], Ag + (size_t)((u)*64) * 2048 + (kb))
#define OSTG_B(bi, u, kb) \
    async_copy16(&Bs[bi][(u)*4096 + ldst], Bg + (size_t)((u)*64) * 2048 + (kb))

__global__ __launch_bounds__(512, 2) void gemm_out(
    const _Float16* __restrict__ A, const _Float16* __restrict__ Bm,
    const float* __restrict__ bias, float* __restrict__ C) {
    __shared__ _Float16 As[2][8192];    // 128 x 64 per buf
    __shared__ _Float16 Bs[2][16384];   // 256 x 64 per buf

    const int tid  = threadIdx.x;
    const int wave = tid >> 6;
    const int lane = tid & 63;
    const int quad = lane >> 4;
    const int l16  = lane & 15;
    const int wr   = wave >> 2;
    const int wc   = wave & 3;

    const int lin = (int)(blockIdx.y * gridDim.x + blockIdx.x);
    const int idx = (lin & 7) * 32 + (lin >> 3);     // nwg = 256
    const int m0  = (idx >> 3) * 128;                // 32 row-tiles
    const int n0  = (idx & 7) * 256;                 // 8 col-tiles

    const int srow = tid >> 3;
    const int sg   = ((tid & 7) ^ (srow & 7)) << 3;
    const _Float16* Ag = A  + (size_t)(m0 + srow) * 2048 + sg;
    const _Float16* Bg = Bm + (size_t)(n0 + srow) * 2048 + sg;
    const int ldst = wave * 512;

    const int sk = l16 & 7;
    const int g0 = ((0 + quad) ^ sk) << 3;
    const int g1 = ((4 + quad) ^ sk) << 3;
    const int abase = wr * 4096 + l16 * 64;
    const int bbase = wc * 4096 + l16 * 64;

    f32x4_t acc[4][4] = {};

    OSTG_A(0, 0, 0);  OSTG_A(0, 1, 0);
    OSTG_B(0, 0, 0);  OSTG_B(0, 1, 0);  OSTG_B(0, 2, 0);  OSTG_B(0, 3, 0);
    OSTG_B(1, 0, 64); OSTG_B(1, 1, 64); OSTG_B(1, 2, 64); OSTG_B(1, 3, 64);
    asm volatile("s_waitcnt vmcnt(4)" ::: "memory");
    BAR;

    for (int t = 0; t < 32; ++t) {
        const int  cur = t & 1;
        const int  kA  = (t + 1) << 6;
        const int  kB  = (t + 2) << 6;
        const bool sA  = (t + 1 < 32);
        const bool sB  = (t + 2 < 32);
        half8_t a[2][2], b[4][2];

        // ph1
#pragma unroll
        for (int mi = 0; mi < 2; ++mi) {
            a[mi][0] = *(const half8_t*)(&As[cur][abase + mi * 1024 + g0]);
            a[mi][1] = *(const half8_t*)(&As[cur][abase + mi * 1024 + g1]);
        }
#pragma unroll
        for (int ni = 0; ni < 4; ++ni) {
            b[ni][0] = *(const half8_t*)(&Bs[cur][bbase + ni * 1024 + g0]);
            b[ni][1] = *(const half8_t*)(&Bs[cur][bbase + ni * 1024 + g1]);
        }
        if (sA) { OSTG_A(cur ^ 1, 0, kA); OSTG_A(cur ^ 1, 1, kA); }
        BAR;
        PRIO1;
#pragma unroll
        for (int mi = 0; mi < 2; ++mi)
#pragma unroll
            for (int ni = 0; ni < 4; ++ni) {
                acc[mi][ni] = __builtin_amdgcn_mfma_f32_16x16x32_f16(a[mi][0], b[ni][0], acc[mi][ni], 0, 0, 0);
                acc[mi][ni] = __builtin_amdgcn_mfma_f32_16x16x32_f16(a[mi][1], b[ni][1], acc[mi][ni], 0, 0, 0);
            }
        PRIO0;
        BAR;
        // ph2
#pragma unroll
        for (int mi = 0; mi < 2; ++mi) {
            a[mi][0] = *(const half8_t*)(&As[cur][abase + (2 + mi) * 1024 + g0]);
            a[mi][1] = *(const half8_t*)(&As[cur][abase + (2 + mi) * 1024 + g1]);
        }
        if (sB) { OSTG_B(cur, 0, kB); OSTG_B(cur, 1, kB);
                  OSTG_B(cur, 2, kB); OSTG_B(cur, 3, kB); }
        BAR;
        PRIO1;
#pragma unroll
        for (int mi = 0; mi < 2; ++mi)
#pragma unroll
            for (int ni = 0; ni < 4; ++ni) {
                acc[2 + mi][ni] = __builtin_amdgcn_mfma_f32_16x16x32_f16(a[mi][0], b[ni][0], acc[2 + mi][ni], 0, 0, 0);
                acc[2 + mi][ni] = __builtin_amdgcn_mfma_f32_16x16x32_f16(a[mi][1], b[ni][1], acc[2 + mi][ni], 0, 0, 0);
            }
        PRIO0;
        if (sB) { asm volatile("s_waitcnt vmcnt(4)" ::: "memory"); }
        else    { asm volatile("s_waitcnt vmcnt(0)" ::: "memory"); }
        BAR;
    }

#pragma unroll
    for (int ni = 0; ni < 4; ++ni) {
        const int c = n0 + wc * 64 + ni * 16 + l16;
        const float bv = bias[c];
#pragma unroll
        for (int mi = 0; mi < 4; ++mi) {
            const int r0 = m0 + wr * 64 + mi * 16 + quad * 4;
#pragma unroll
            for (int i = 0; i < 4; ++i)
                C[(size_t)(r0 + i) * HIDDEN + c] = acc[mi][ni][i] + bv;
        }
    }
}

// ---------------------------------------------------------------------------
// GQA flash attention, transposed-score, NO-MAX softmax.
// 512 thr = 8 waves = 4 g-heads x 2 q-halves (32 rows). Changes this round:
//  * ones-trick MFMA REMOVED: row sums as per-lane f32 VALU adds (each lane
//    sums its quad's k-slice for q=l16), one 2-step __shfl_xor reduce at end.
//    Saves ~11% of MFMA pipe (the critical pipe at 58% util).
//  * V fragments paired (dt even/odd contiguous 8 halves): 16 4-way-conflict
//    ds_read_b64 -> 8 conflict-free ds_read_b128 per tile per wave.
//  * 4-slot KV buffers, 2 tiles per iteration -> 16 barriers instead of 32.
//  * s_setprio(1) around MFMA clusters (T5; +4-7% attn per m191).
// ---------------------------------------------------------------------------
__global__ __launch_bounds__(512, 4) void attn_kernel(
    const _Float16* __restrict__ Qb, const _Float16* __restrict__ Kf,
    const _Float16* __restrict__ Vf, _Float16* __restrict__ ctx) {
    __shared__ _Float16 S[32768];   // K: slot*4096 | V: 16384 + slot*4096

    const int tid  = threadIdx.x;
    const int wave = tid >> 6;
    const int lane = tid & 63;
    const int quad = lane >> 4;
    const int l16  = lane & 15;
    const int qs   = wave >> 2;             // 0..1 : q-half (32 rows)
    const int wh   = wave & 3;              // 0..3 : g-head
    const int qt  = blockIdx.x;             // 64-row q-tile
    const int bkv = blockIdx.y;
    const int b   = bkv >> 3;
    const int kv  = bkv & 7;
    const int h   = kv * 4 + wh;

    half8_t qa[2][2];
#pragma unroll
    for (int g = 0; g < 2; ++g) {
        const _Float16* qp = Qb +
            ((size_t)(b * SEQ + qt * 64 + qs * 32 + g * 16 + l16)) * HIDDEN +
            h * 64 + quad * 8;
        qa[g][0] = *(const half8_t*)qp;
        qa[g][1] = *(const half8_t*)(qp + 32);
    }

    f32x4_t ot[2][4] = {};                  // O^T accum per group
    float fl[2] = {0.f, 0.f};               // per-lane partial row sums

    const size_t kvbase = (size_t)(b * 8 + kv) * 32 * 4096;  // halves
    const int sh = wave * 512 + lane * 8;

    // prologue: tiles 0,1 -> slots 0,1
#pragma unroll
    for (int t = 0; t < 2; ++t) {
        async_copy16(&S[t * 4096 + wave * 512],         Kf + kvbase + (size_t)t * 4096 + sh);
        async_copy16(&S[16384 + t * 4096 + wave * 512], Vf + kvbase + (size_t)t * 4096 + sh);
    }

    for (int j = 0; j < 16; ++j) {
        __syncthreads();                     // drains tiles 2j,2j+1 copies
        if (j < 15) {
#pragma unroll
            for (int t = 0; t < 2; ++t) {
                const int tile = 2 * j + 2 + t;
                const int slot = tile & 3;
                const size_t off = kvbase + (size_t)tile * 4096 + sh;
                async_copy16(&S[slot * 4096 + wave * 512],         Kf + off);
                async_copy16(&S[16384 + slot * 4096 + wave * 512], Vf + off);
            }
        }
#pragma unroll
        for (int tt = 0; tt < 2; ++tt) {
            const int slot = (2 * j + tt) & 3;
            const int kb = slot * 4096, vb = 16384 + slot * 4096;
#pragma unroll
            for (int nt = 0; nt < 4; ++nt) {
                const half8_t kf0 = *(const half8_t*)(&S[kb + ((nt * 2 + 0) * 64 + lane) * 8]);
                const half8_t kf1 = *(const half8_t*)(&S[kb + ((nt * 2 + 1) * 64 + lane) * 8]);
                half4_t p[2];
#pragma unroll
                for (int g = 0; g < 2; ++g) {
                    f32x4_t s = {};
                    PRIO1;
                    s = __builtin_amdgcn_mfma_f32_16x16x32_f16(kf0, qa[g][0], s, 0, 0, 0);
                    s = __builtin_amdgcn_mfma_f32_16x16x32_f16(kf1, qa[g][1], s, 0, 0, 0);
                    PRIO0;
                    const float e0 = __builtin_amdgcn_exp2f(s[0]);
                    const float e1 = __builtin_amdgcn_exp2f(s[1]);
                    const float e2 = __builtin_amdgcn_exp2f(s[2]);
                    const float e3 = __builtin_amdgcn_exp2f(s[3]);
                    fl[g] += (e0 + e1) + (e2 + e3);
                    const fp16x2_t lo = __builtin_amdgcn_cvt_pkrtz(e0, e1);
                    const fp16x2_t hi = __builtin_amdgcn_cvt_pkrtz(e2, e3);
                    half4_t pv;
                    pv[0] = (_Float16)lo[0]; pv[1] = (_Float16)lo[1];
                    pv[2] = (_Float16)hi[0]; pv[3] = (_Float16)hi[1];
                    p[g] = pv;
                }
#pragma unroll
                for (int dp = 0; dp < 2; ++dp) {
                    const half8_t vv = *(const half8_t*)(&S[vb + ((nt * 2 + dp) * 64 + lane) * 8]);
                    const half4_t vlo = {vv[0], vv[1], vv[2], vv[3]};
                    const half4_t vhi = {vv[4], vv[5], vv[6], vv[7]};
                    PRIO1;
                    ot[0][dp * 2]     = __builtin_amdgcn_mfma_f32_16x16x16f16(vlo, p[0], ot[0][dp * 2], 0, 0, 0);
                    ot[1][dp * 2]     = __builtin_amdgcn_mfma_f32_16x16x16f16(vlo, p[1], ot[1][dp * 2], 0, 0, 0);
                    ot[0][dp * 2 + 1] = __builtin_amdgcn_mfma_f32_16x16x16f16(vhi, p[0], ot[0][dp * 2 + 1], 0, 0, 0);
                    ot[1][dp * 2 + 1] = __builtin_amdgcn_mfma_f32_16x16x16f16(vhi, p[1], ot[1][dp * 2 + 1], 0, 0, 0);
                    PRIO0;
                }
            }
        }
    }

    // full row sums: combine the 4 quads' partials (lanes l16+16q share q-col)
#pragma unroll
    for (int g = 0; g < 2; ++g) {
        fl[g] += __shfl_xor(fl[g], 16);
        fl[g] += __shfl_xor(fl[g], 32);
    }

    // epilogue: O^T -> O via per-wave LDS transpose, coalesced ctx writes.
    __syncthreads();                         // KV buffers dead
    _Float16* T = S + wave * 1152;           // 16 rows x 72 (pad vs bank clash)
#pragma unroll
    for (int g = 0; g < 2; ++g) {
        const float inv = 1.f / fl[g];
#pragma unroll
        for (int dt = 0; dt < 4; ++dt) {
            half4_t hh;
#pragma unroll
            for (int r = 0; r < 4; ++r) hh[r] = (_Float16)(ot[g][dt][r] * inv);
            *(half4_t*)(T + l16 * 72 + dt * 16 + quad * 4) = hh;
        }
        __builtin_amdgcn_s_waitcnt(0);       // lgkm drain: wave-internal LDS RAW
        _Float16* cp = ctx +
            (((size_t)b * 32 + h) * SEQ + qt * 64 + qs * 32 + g * 16 + l16) * 64;
#pragma unroll
        for (int pass = 0; pass < 2; ++pass) {
            const half8_t row = *(const half8_t*)(T + l16 * 72 + pass * 32 + quad * 8);
            *(half8_t*)(cp + pass * 32 + quad * 8) = row;
        }
        __builtin_amdgcn_s_waitcnt(0);       // before next group overwrites T
    }
}

// ---------------------------------------------------------------------------
// single fused prep kernel: all fp32->fp16 casts + bias packing
// ---------------------------------------------------------------------------
__device__ __forceinline__ void cast4(const float* __restrict__ s,
                                      _Float16* __restrict__ d, int i, float sc) {
    const f32x4_t v = ((const f32x4_t*)s)[i];
    half4_t h;
#pragma unroll
    for (int j = 0; j < 4; ++j) h[j] = (_Float16)(v[j] * sc);
    ((half4_t*)d)[i] = h;
}

__global__ __launch_bounds__(256) void prep(
    const float* __restrict__ X,  const float* __restrict__ Wq,
    const float* __restrict__ Wk, const float* __restrict__ Wv,
    const float* __restrict__ Wo, const float* __restrict__ bq,
    const float* __restrict__ bk, const float* __restrict__ bv,
    _Float16* __restrict__ Xh, _Float16* __restrict__ Wqkv,
    _Float16* __restrict__ Woh, float* __restrict__ bqkv) {
    const int bid = blockIdx.x, tid = threadIdx.x;
    if (bid < 8192)       cast4(X,  Xh,   bid * 256 + tid, 1.f);
    else if (bid < 12288) cast4(Wq, Wqkv, (bid - 8192) * 256 + tid, SCALEQ);
    else if (bid < 13312) cast4(Wk, Wqkv + (size_t)HIDDEN * HIDDEN, (bid - 12288) * 256 + tid, 1.f);
    else if (bid < 14336) cast4(Wv, Wqkv + (size_t)(HIDDEN + 512) * HIDDEN, (bid - 13312) * 256 + tid, 1.f);
    else if (bid < 18432) cast4(Wo, Woh,  (bid - 14336) * 256 + tid, 1.f);
    else {
        const int i = (bid - 18432) * 256 + tid;
        if (i < 2048)      bqkv[i] = bq[i] * SCALEQ;
        else if (i < 2560) bqkv[i] = bk[i - 2048];
        else if (i < 3072) bqkv[i] = bv[i - 2560];
    }
}

// ---------------------------------------------------------------------------
extern "C" void kernel_launch(void* const* d_in, const int* in_sizes, int n_in,
                              void* d_out, int out_size, void* d_ws, size_t ws_size,
                              hipStream_t stream) {
    const float* X  = (const float*)d_in[0];
    const float* Wq = (const float*)d_in[1];
    const float* bq = (const float*)d_in[2];
    const float* Wk = (const float*)d_in[3];
    const float* bk = (const float*)d_in[4];
    const float* Wv = (const float*)d_in[5];
    const float* bv = (const float*)d_in[6];
    const float* Wo = (const float*)d_in[7];
    const float* bo = (const float*)d_in[8];
    float* out = (float*)d_out;

    char* p = (char*)d_ws;
    _Float16* Xh   = (_Float16*)p; p += (size_t)MROWS * HIDDEN * 2;   // 16.8 MB (reused as ctx)
    _Float16* Wqkv = (_Float16*)p; p += (size_t)NQKV * HIDDEN * 2;    // 12.6 MB
    _Float16* Woh  = (_Float16*)p; p += (size_t)HIDDEN * HIDDEN * 2;  //  8.4 MB
    float*    bqkv = (float*)p;    p += (size_t)NQKV * 4;
    _Float16* Qb   = (_Float16*)p; p += (size_t)MROWS * HIDDEN * 2;   // 16.8 MB
    _Float16* Kfb  = (_Float16*)p; p += (size_t)16 * 32 * 4096 * 2;   //  4.2 MB frag-packed
    _Float16* Vfb  = (_Float16*)p; p += (size_t)16 * 32 * 4096 * 2;   //  4.2 MB frag-packed (paired)
    _Float16* ctx  = Xh;  // alias: Xh dead after QKV GEMM

    prep<<<18444, 256, 0, stream>>>(X, Wq, Wk, Wv, Wo, bq, bk, bv,
                                    Xh, Wqkv, Woh, bqkv);

    // QKV projection: grid 16x32 = 512 blocks = exactly 2/CU (100% fill)
    gemm_qkv<<<dim3(NQKV / 192, MROWS / 128), 512, 0, stream>>>(
        Xh, Wqkv, bqkv, Qb, Kfb, Vfb);

    // attention -> ctx [b][h][s][d] fp16 (512 blocks x 512 thr)
    attn_kernel<<<dim3(SEQ / 64, BATCH * NKV), 512, 0, stream>>>(Qb, Kfb, Vfb, ctx);

    // output projection: grid 8x32 = 256 blocks -> exact machine fill
    gemm_out<<<dim3(HIDDEN / 256, MROWS / 128), 512, 0, stream>>>(
        ctx, Woh, bo, out);
}